// Round 6
// baseline (1819.369 us; speedup 1.0000x reference)
//
#include <hip/hip_runtime.h>
#include <cstddef>
#include <cstdint>

// ---- model dims ----
#define L_TOK 392
#define BATCH 8
#define DM    768
#define ED    1536
#define NST   16
#define DTR   48
#define ROWS  (BATCH * L_TOK)   // 3136

// chunked scan
#define C_CH 8
#define CLEN 49                 // L_TOK / C_CH
#define EGB  24                 // ED/64 e-groups

// x_proj split-K (6 so POUT [6.02MB] + DBC48/DTWB/OWB fit in d_out)
#define XP_Z  6

// Workspace ~49 MB -- do NOT grow d_ws. Scratch with disjoint lifetimes
// (x_proj partials POUT, scan summaries HEND/SDL, bf16 copies DBC48/DTWB/OWB)
// lives in d_out, dead until out_transpose. bf16 weight copies alias dead ws
// buffers (see launch).

typedef unsigned short ushortT;
typedef __bf16 bf16x8 __attribute__((ext_vector_type(8)));
typedef unsigned short us8 __attribute__((ext_vector_type(8)));
typedef unsigned short us4 __attribute__((ext_vector_type(4)));
typedef float f32x4 __attribute__((ext_vector_type(4)));

#define LOG2E 1.4426950408889634f

__device__ __forceinline__ float bf2f(ushortT u) {
    union { unsigned int i; float f; } v; v.i = ((unsigned int)u) << 16; return v.f;
}
__device__ __forceinline__ ushortT f2bf(float f) {
    union { float f; unsigned int i; } v; v.f = f;
    unsigned int r = v.i + 0x7FFFu + ((v.i >> 16) & 1u);   // round-nearest-even
    return (ushortT)(r >> 16);
}

// async global->LDS, 16B per lane; LDS dest is wave-uniform base + lane*16.
__device__ __forceinline__ void gload16(const void* g, void* l) {
    __builtin_amdgcn_global_load_lds(
        (const __attribute__((address_space(1))) void*)g,
        (__attribute__((address_space(3))) void*)l, 16, 0, 0);
}

enum { EPI_STORE = 0, EPI_BIAS = 1, EPI_BIAS_SOFTPLUS = 2, EPI_ADD = 3 };

#define INW_F4 (2 * ED * DM / 4)   // 589824
#define XW_F4  (80 * ED / 4)       // 30720
#define OW_F4  (DM * ED / 4)       // 294912
#define DTW_U  (ED * 16)           // 24576 us4 units of [1536][64] padded dtw
#define PE_F4  (DM * DM / 4)       // 147456

// ----------------------------------------------------------------------------
// Per-layer prep, one dispatch:
//   blocks [0, ROWS): rmsnorm row r -> XN bf16
//   blocks [ROWS, ..): convert in_w/xw/ow fp32->bf16, dtw -> [1536][64]
//                      bf16 zero-padded (K=48 padded to 64 for MFMA dt_proj)
// ----------------------------------------------------------------------------
__global__ __launch_bounds__(256)
void prep_kernel(const float* __restrict__ in_w, ushortT* __restrict__ inwb,
                 const float* __restrict__ xw,   ushortT* __restrict__ xwb,
                 const float* __restrict__ ow,   ushortT* __restrict__ owb,
                 const float* __restrict__ dtw,  ushortT* __restrict__ dtwb,
                 const float* __restrict__ x,    const float* __restrict__ nw,
                 ushortT* __restrict__ xn)
{
    if (blockIdx.x < ROWS) {
        // ---- rmsnorm ----
        int r = blockIdx.x;
        const float* xr = x + (size_t)r * DM;
        float v[3];
        float s = 0.f;
#pragma unroll
        for (int i = 0; i < 3; ++i) {
            v[i] = xr[threadIdx.x + i * 256];
            s += v[i] * v[i];
        }
#pragma unroll
        for (int o = 32; o > 0; o >>= 1) s += __shfl_down(s, o, 64);
        __shared__ float wsum[4];
        __shared__ float scale_s;
        int wave = threadIdx.x >> 6;
        if ((threadIdx.x & 63) == 0) wsum[wave] = s;
        __syncthreads();
        if (threadIdx.x == 0) {
            float t = wsum[0] + wsum[1] + wsum[2] + wsum[3];
            scale_s = rsqrtf(t * (1.f / 768.f) + 1e-5f);
        }
        __syncthreads();
        float sc = scale_s;
#pragma unroll
        for (int i = 0; i < 3; ++i) {
            int d = threadIdx.x + i * 256;
            xn[(size_t)r * DM + d] = f2bf(v[i] * sc * nw[d]);
        }
        return;
    }
    // ---- conversions ----
    int idx = (blockIdx.x - ROWS) * 256 + threadIdx.x;
    if (idx < INW_F4 + XW_F4 + OW_F4) {
        const float* s; ushortT* d;
        if (idx < INW_F4) { s = in_w; d = inwb; }
        else if (idx < INW_F4 + XW_F4) { idx -= INW_F4; s = xw; d = xwb; }
        else { idx -= INW_F4 + XW_F4; s = ow; d = owb; }
        float4 f = *(const float4*)(s + (size_t)idx * 4);
        us4 h; h.x = f2bf(f.x); h.y = f2bf(f.y); h.z = f2bf(f.z); h.w = f2bf(f.w);
        *(us4*)(d + (size_t)idx * 4) = h;
    } else if (idx < INW_F4 + XW_F4 + OW_F4 + DTW_U) {
        int u = idx - (INW_F4 + XW_F4 + OW_F4);
        int row = u >> 4;
        int c4  = (u & 15) * 4;
        us4 h = {0, 0, 0, 0};
        if (c4 < DTR) {
            float4 f = *(const float4*)(dtw + (size_t)row * DTR + c4);
            h.x = f2bf(f.x); h.y = f2bf(f.y); h.z = f2bf(f.z); h.w = f2bf(f.w);
        }
        *(us4*)(dtwb + (size_t)row * 64 + c4) = h;
    }
}

// ----------------------------------------------------------------------------
// Pipelined MFMA GEMM: C[M,N] (epi)= A[M,K](bf16) @ W[N,K](bf16)^T
// Tile (WM*64)x128, BK=32, WM*2 waves (WMx2), 4x4 mfma_f32_16x16x32_bf16/wave.
// WM=2: 128x128/256thr (default); WM=4: 256x128/512thr (in_proj -- doubles
// MFMA work per staging interval, halves W traffic; better latency cover).
// Staging via global_load_lds width=16; simple 2-phase double-buffer with
// __syncthreads (counted-vmcnt 3-deep measured neutral in r5 -- removed).
// LDS linear rows of 64B: staging writes and quad-slot ds_read_b128 reads
// both bank-uniform. Tail rows read in-bounds garbage from adjacent buffers;
// they only affect unstored C entries.
// SPLITK: blockIdx.z covers kchunk; ATOMIC: fp32 atomicAdd epilogue;
// PARTIAL: plain fp32 stores to per-z slices;
// SPLIT: block-uniform output split at column ED (in_proj -> XC | Zb).
// ----------------------------------------------------------------------------
template <int EPI, bool C_BF, bool SPLIT, bool ATOMIC, bool PARTIAL, int WM = 2>
__global__ __launch_bounds__(WM * 128)
void gemm_mfma(const ushortT* __restrict__ A, int lda,
               const ushortT* __restrict__ W, int ldw,
               const float* __restrict__ bias,
               void* __restrict__ Cv, void* __restrict__ Cv2, int ldc,
               int M, int N, int K, int kchunk)
{
    __shared__ ushortT As[2][WM * 64 * 32];
    __shared__ ushortT Ws[2][128 * 32];

    const int tid  = threadIdx.x;
    const int lane = tid & 63;
    const int wave = tid >> 6;
    const int wm   = wave >> 1;        // 0..WM-1
    const int wn   = wave & 1;         // 0..1
    const int quad = lane >> 4;        // 0..3
    const int l16  = lane & 15;        // 0..15

    // XCD-chunked bijective swizzle (m204): each XCD gets a contiguous chunk
    // of x-major flat ids -> blocks sharing an A row-panel share an L2.
    const int gx   = gridDim.x;
    const int nwg  = gx * gridDim.y;
    const int flat = blockIdx.y * gx + blockIdx.x;
    const int q = nwg >> 3, r = nwg & 7;
    const int xcd = flat & 7, sidx = flat >> 3;
    const int swz = (xcd < r ? xcd * (q + 1) : r * (q + 1) + (xcd - r) * q) + sidx;

    const int m0 = (swz / gx) * (WM * 64);
    const int n0 = (swz % gx) * 128;
    const int kb = blockIdx.z * kchunk;
    const int KT = kchunk / 32;

    // staging geometry: A has WM*4 segs of 16 rows, W has 8 segs; per wave:
    // 2 A segs + 8/(WM*2) W segs. lane covers row seg*16 + (lane>>2),
    // 16B col-slot (lane&3).
    const int srow = lane >> 2;
    const int scol = (lane & 3) * 8;
    const ushortT* aBase = A + (size_t)(m0 + srow) * lda + scol;
    const ushortT* wBase = W + (size_t)(n0 + srow) * ldw + scol;

    auto stage = [&](int buf, int k0) {
#pragma unroll
        for (int c = 0; c < 2; ++c) {
            const int seg = wave * 2 + c;
            gload16(aBase + (size_t)(seg * 16) * lda + k0, &As[buf][seg * 512]);
        }
#pragma unroll
        for (int c = 0; c < 8 / (WM * 2); ++c) {
            const int seg = wave * (8 / (WM * 2)) + c;
            gload16(wBase + (size_t)(seg * 16) * ldw + k0, &Ws[buf][seg * 512]);
        }
    };

    f32x4 acc[4][4] = {};

    auto compute = [&](int buf) {
        bf16x8 af[4], bw[4];
#pragma unroll
        for (int t = 0; t < 4; ++t) {
            us8 ta = *(const us8*)&As[buf][(wm * 64 + t * 16 + l16) * 32 + quad * 8];
            af[t] = __builtin_bit_cast(bf16x8, ta);
            us8 tb = *(const us8*)&Ws[buf][(wn * 64 + t * 16 + l16) * 32 + quad * 8];
            bw[t] = __builtin_bit_cast(bf16x8, tb);
        }
#pragma unroll
        for (int i = 0; i < 4; ++i)
#pragma unroll
            for (int j = 0; j < 4; ++j)
                acc[i][j] = __builtin_amdgcn_mfma_f32_16x16x32_bf16(
                    af[i], bw[j], acc[i][j], 0, 0, 0);
    };

    stage(0, kb);
    __syncthreads();

    for (int kt = 0; kt < KT; ++kt) {
        if (kt + 1 < KT) stage((kt & 1) ^ 1, kb + (kt + 1) * 32);  // issue early
        compute(kt & 1);
        __syncthreads();   // drains vmcnt -> next buffer ready
    }

#pragma unroll
    for (int i = 0; i < 4; ++i) {
#pragma unroll
        for (int r2 = 0; r2 < 4; ++r2) {
            int gm = m0 + wm * 64 + i * 16 + quad * 4 + r2;
            if (gm >= M) continue;
#pragma unroll
            for (int j = 0; j < 4; ++j) {
                int gn = n0 + wn * 64 + j * 16 + l16;
                if (gn >= N) continue;
                float v = acc[i][j][r2];
                if (EPI == EPI_BIAS) v += bias[gn];
                if (EPI == EPI_BIAS_SOFTPLUS) {
                    v += bias[gn];
                    v = fmaxf(v, 0.f) + log1pf(expf(-fabsf(v)));  // softplus
                }
                void* dst = Cv;
                int cn = gn;
                if (SPLIT && gn >= ED) { dst = Cv2; cn = gn - ED; }  // block-uniform
                size_t off = (size_t)gm * ldc + cn;
                if (PARTIAL) {
                    ((float*)dst)[(size_t)blockIdx.z * M * ldc + off] = v;
                } else if (ATOMIC) {
                    atomicAdd((float*)dst + off, v);
                } else if (C_BF) {
                    ((ushortT*)dst)[off] = f2bf(v);
                } else {
                    float* p = (float*)dst + off;
                    *p = (EPI == EPI_ADD) ? v + *p : v;
                }
            }
        }
    }
}

// ----------------------------------------------------------------------------
// Reduce x_proj split-K partials: DBC[idx] = sum_z POUT[z][idx].
// Also emits DBC48 bf16 [ROWS][64]: cols 0..47 = dbc, 48..63 = 0 (explicit --
// stale d_out bytes reinterpreted as bf16 could be NaN/Inf) for MFMA dt_proj.
// ----------------------------------------------------------------------------
__global__ __launch_bounds__(256)
void reduce_partials_kernel(const float* __restrict__ P, float* __restrict__ dbc,
                            ushortT* __restrict__ dbc48)
{
    int idx = blockIdx.x * 256 + threadIdx.x;
    if (idx < ROWS * 80) {
        float s = 0.f;
#pragma unroll
        for (int z = 0; z < XP_Z; ++z)
            s += P[(size_t)z * ROWS * 80 + idx];
        dbc[idx] = s;
        int r = idx / 80, c = idx % 80;
        if (c < DTR) dbc48[(size_t)r * 64 + c] = f2bf(s);
    } else {
        int t = idx - ROWS * 80;
        if (t < ROWS * 16) {
            int r = t >> 4, c = DTR + (t & 15);
            dbc48[(size_t)r * 64 + c] = 0;   // bf16 +0
        }
    }
}

// ----------------------------------------------------------------------------
// Causal depthwise conv (width 4) + bias + silu.
// ----------------------------------------------------------------------------
__global__ __launch_bounds__(256)
void conv_silu_kernel(const ushortT* __restrict__ xc, const float* __restrict__ cw,
                      const float* __restrict__ cb, ushortT* __restrict__ xin)
{
    int idx = blockIdx.x * 256 + threadIdx.x;
    if (idx >= ROWS * ED) return;
    int e = idx % ED;
    int r = idx / ED;
    int l = r % L_TOK;
    float w0 = cw[e * 4 + 0], w1 = cw[e * 4 + 1];
    float w2 = cw[e * 4 + 2], w3 = cw[e * 4 + 3];
    const ushortT* base = xc + (size_t)r * ED + e;
    float acc = cb[e] + w3 * bf2f(base[0]);
    if (l >= 1) acc += w2 * bf2f(base[-(ptrdiff_t)ED]);
    if (l >= 2) acc += w1 * bf2f(base[-(ptrdiff_t)(2 * ED)]);
    if (l >= 3) acc += w0 * bf2f(base[-(ptrdiff_t)(3 * ED)]);
    xin[(size_t)r * ED + e] = f2bf(acc / (1.f + __expf(-acc)));  // silu
}

// ----------------------------------------------------------------------------
// Chunked selective scan, pass 1: per (b,e,chunk) local end-state + sum_delta.
// a[] is pre-scaled by log2(e) so the inner loop uses raw v_exp_f32 (2^x).
// ----------------------------------------------------------------------------
__global__ __launch_bounds__(64)
void scan_part1(const ushortT* __restrict__ delta, const ushortT* __restrict__ xin,
                const float* __restrict__ dbc, const float* __restrict__ a_log,
                float* __restrict__ hend, float* __restrict__ sdl)
{
    __shared__ float BsL[CLEN * 16];
    const int tid = threadIdx.x;
    const int bid = blockIdx.x;
    const int eg = bid % EGB;
    const int c  = (bid / EGB) % C_CH;
    const int b  = bid / (EGB * C_CH);
    const int e  = eg * 64 + tid;
    const int l0 = c * CLEN;
    const int rb = b * L_TOK + l0;

    for (int i = tid; i < CLEN * 16; i += 64) {
        int s = i >> 4, n = i & 15;
        BsL[i] = dbc[(size_t)(rb + s) * 80 + 48 + n];
    }
    __syncthreads();

    float a[16];
    const float* ar = a_log + (size_t)e * 16;
#pragma unroll
    for (int n = 0; n < 16; ++n) a[n] = -__expf(ar[n]) * LOG2E;

    float h[16];
#pragma unroll
    for (int n = 0; n < 16; ++n) h[n] = 0.f;
    float sum_dl = 0.f;

    const size_t base = (size_t)rb * ED + e;
    float rdl[7], rxi[7];
#pragma unroll
    for (int j = 0; j < 7; ++j) {
        rdl[j] = bf2f(delta[base + (size_t)j * ED]);
        rxi[j] = bf2f(xin[base + (size_t)j * ED]);
    }
    for (int s0 = 0; s0 < CLEN; s0 += 7) {
#pragma unroll
        for (int j = 0; j < 7; ++j) {
            const int s = s0 + j;
            float dl = rdl[j], xi = rxi[j];
            int sp = s + 7; if (sp > CLEN - 1) sp = CLEN - 1;   // clamped prefetch
            rdl[j] = bf2f(delta[base + (size_t)sp * ED]);
            rxi[j] = bf2f(xin[base + (size_t)sp * ED]);
            float dlxi = dl * xi;
            sum_dl += dl;
#pragma unroll
            for (int n = 0; n < 16; ++n)
                h[n] = __builtin_amdgcn_exp2f(dl * a[n]) * h[n] + dlxi * BsL[s * 16 + n];
        }
    }

    float* hp = hend + (((size_t)b * ED + e) * C_CH + c) * 16;
#pragma unroll
    for (int n = 0; n < 16; ++n) hp[n] = h[n];
    sdl[((size_t)b * ED + e) * C_CH + c] = sum_dl;
}

// ----------------------------------------------------------------------------
// Chunked scan, pass 2: combine predecessor summaries, re-run chunk, emit y.
// ----------------------------------------------------------------------------
__global__ __launch_bounds__(64)
void scan_part2(const ushortT* __restrict__ delta, const ushortT* __restrict__ xin,
                const float* __restrict__ dbc, const ushortT* __restrict__ zb,
                const float* __restrict__ a_log, const float* __restrict__ dvec,
                const float* __restrict__ hend, const float* __restrict__ sdl,
                ushortT* __restrict__ y)
{
    __shared__ float BsL[CLEN * 16];
    __shared__ float CsL[CLEN * 16];
    const int tid = threadIdx.x;
    const int bid = blockIdx.x;
    const int eg = bid % EGB;
    const int c  = (bid / EGB) % C_CH;
    const int b  = bid / (EGB * C_CH);
    const int e  = eg * 64 + tid;
    const int l0 = c * CLEN;
    const int rb = b * L_TOK + l0;

    for (int i = tid; i < CLEN * 16; i += 64) {
        int s = i >> 4, n = i & 15;
        size_t row = (size_t)(rb + s) * 80;
        BsL[i] = dbc[row + 48 + n];
        CsL[i] = dbc[row + 64 + n];
    }
    __syncthreads();

    float a[16];
    const float* ar = a_log + (size_t)e * 16;
#pragma unroll
    for (int n = 0; n < 16; ++n) a[n] = -__expf(ar[n]) * LOG2E;
    const float dcf = dvec[e];

    float h[16];
#pragma unroll
    for (int n = 0; n < 16; ++n) h[n] = 0.f;
    const float* hb = hend + (((size_t)b * ED + e) * C_CH) * 16;
    const float* sb = sdl + ((size_t)b * ED + e) * C_CH;
    for (int cc = 0; cc < c; ++cc) {
        float sv = sb[cc];
#pragma unroll
        for (int n = 0; n < 16; ++n)
            h[n] = __builtin_amdgcn_exp2f(a[n] * sv) * h[n] + hb[cc * 16 + n];
    }

    const size_t base = (size_t)rb * ED + e;
    float rdl[7], rxi[7], rz[7];
#pragma unroll
    for (int j = 0; j < 7; ++j) {
        rdl[j] = bf2f(delta[base + (size_t)j * ED]);
        rxi[j] = bf2f(xin[base + (size_t)j * ED]);
        rz[j]  = bf2f(zb[base + (size_t)j * ED]);
    }
    for (int s0 = 0; s0 < CLEN; s0 += 7) {
#pragma unroll
        for (int j = 0; j < 7; ++j) {
            const int s = s0 + j;
            float dl = rdl[j], xi = rxi[j], z = rz[j];
            int sp = s + 7; if (sp > CLEN - 1) sp = CLEN - 1;   // clamped prefetch
            rdl[j] = bf2f(delta[base + (size_t)sp * ED]);
            rxi[j] = bf2f(xin[base + (size_t)sp * ED]);
            rz[j]  = bf2f(zb[base + (size_t)sp * ED]);
            float dlxi = dl * xi;
            float yv = 0.f;
#pragma unroll
            for (int n = 0; n < 16; ++n) {
                h[n] = __builtin_amdgcn_exp2f(dl * a[n]) * h[n] + dlxi * BsL[s * 16 + n];
                yv += h[n] * CsL[s * 16 + n];
            }
            yv += dcf * xi;
            float sz = z / (1.f + __expf(-z));
            y[base + (size_t)s * ED] = f2bf(yv * sz);
        }
    }
}

// ----------------------------------------------------------------------------
// im2col for patch embed + pe_w fp32->bf16 convert (fused, block-range split).
// ----------------------------------------------------------------------------
__global__ __launch_bounds__(256)
void im2col_kernel(const float* __restrict__ rgb, const float* __restrict__ timg,
                   ushortT* __restrict__ P,
                   const float* __restrict__ pe_w, ushortT* __restrict__ peb)
{
    int idx = blockIdx.x * 256 + threadIdx.x;
    if (idx < ROWS * DM) {
        int k = idx % DM;
        int r = idx / DM;
        int b = r / L_TOK;
        int l = r % L_TOK;
        const float* img = (l < 196) ? rgb : timg;
        int p  = (l < 196) ? l : l - 196;
        int py = p / 14, px = p % 14;
        int c  = k >> 8;
        int ph = (k >> 4) & 15;
        int pw = k & 15;
        P[idx] = f2bf(img[(((size_t)b * 3 + c) * 224 + (py * 16 + ph)) * 224 + (px * 16 + pw)]);
        return;
    }
    int u = idx - ROWS * DM;
    if (u < PE_F4) {
        float4 f = *(const float4*)(pe_w + (size_t)u * 4);
        us4 h; h.x = f2bf(f.x); h.y = f2bf(f.y); h.z = f2bf(f.z); h.w = f2bf(f.w);
        *(us4*)(peb + (size_t)u * 4) = h;
    }
}

// ----------------------------------------------------------------------------
// Output: out[(l*768 + d)*8 + b] = x[b, l, d]
// ----------------------------------------------------------------------------
__global__ __launch_bounds__(256)
void out_transpose_kernel(const float* __restrict__ x, float* __restrict__ out)
{
    int idx = blockIdx.x * 256 + threadIdx.x;
    if (idx >= ROWS * DM) return;
    int b = idx & 7;
    int d = (idx >> 3) % DM;
    int l = idx / (8 * DM);
    out[idx] = x[((size_t)(b * L_TOK + l)) * DM + d];
}

// ----------------------------------------------------------------------------
extern "C" void kernel_launch(void* const* d_in, const int* in_sizes, int n_in,
                              void* d_out, int out_size, void* d_ws, size_t ws_size,
                              hipStream_t stream)
{
    (void)in_sizes; (void)n_in; (void)out_size; (void)ws_size;

    const float* rgb  = (const float*)d_in[0];
    const float* timg = (const float*)d_in[1];
    const float* pe_w = (const float*)d_in[2];   // [768, 3,16,16] -> [768][768]
    const float* pe_b = (const float*)d_in[3];
    const float* in_w = (const float*)d_in[4];   // [8, 3072, 768]
    const float* cw   = (const float*)d_in[5];   // [8, 1536, 1, 4]
    const float* cb   = (const float*)d_in[6];   // [8, 1536]
    const float* xw   = (const float*)d_in[7];   // [8, 80, 1536]
    const float* dtw  = (const float*)d_in[8];   // [8, 1536, 48]
    const float* dtb  = (const float*)d_in[9];   // [8, 1536]
    const float* alog = (const float*)d_in[10];  // [8, 1536, 16]
    const float* dvec = (const float*)d_in[11];  // [8, 1536]
    const float* ow   = (const float*)d_in[12];  // [8, 768, 1536]
    const float* nw   = (const float*)d_in[13];  // [8, 768]

    char* p = (char*)d_ws;
    float*   X   = (float*)p;    p += (size_t)ROWS * DM * 4;
    ushortT* XC  = (ushortT*)p;  p += (size_t)ROWS * ED * 2;   // conv-in / patches / y
    ushortT* Zb  = (ushortT*)p;  p += (size_t)ROWS * ED * 2;
    ushortT* XIN = (ushortT*)p;  p += (size_t)ROWS * ED * 2;
    ushortT* DEL = (ushortT*)p;  p += (size_t)ROWS * ED * 2;   // delta; front = xn
    float*   DBC = (float*)p;    p += (size_t)ROWS * 80 * 4;
    ushortT* XN  = DEL;          // overlay: xn dead before delta is written

    // bf16 weight copies, aliased onto dead buffers (lifetimes checked):
    //   INWB in XIN  : written at prep, read by in_proj, dies at conv_silu
    //   XWB  in DBC  : written at prep, read by x_proj, dies at reduce
    //   PEB  in Zb   : written before patch gemm, dies at layer0 in_proj
    ushortT* INWB = XIN;
    ushortT* XWB  = (ushortT*)DBC;
    ushortT* PEB  = Zb;

    // d_out scratch layout (dead until out_transpose):
    //   POUT : [0, 6.02M)          x_proj fp32 partials, dies at reduce
    //   DBC48: [6.02M, 6.42M)      bf16 [ROWS][64], born at reduce, dies dt_proj
    //   DTWB : [6.42M, 6.62M)      bf16 [1536][64], born at prep, dies dt_proj
    //   HEND : [0, 6.29M) + SDL [6.29M, 6.68M)  born scan1 (after dt_proj)
    //   OWB  : [6.68M, 9.04M)      bf16 ow copy, born prep, dies out_proj
    float* POUT = (float*)d_out;
    float* HEND = (float*)d_out;
    float* SDL  = HEND + (size_t)BATCH * ED * C_CH * 16;
    ushortT* DBC48 = (ushortT*)((char*)d_out + (size_t)XP_Z * ROWS * 80 * 4);
    ushortT* DTWB  = DBC48 + (size_t)ROWS * 64;
    ushortT* OWB = (ushortT*)((char*)d_out +
                   ((size_t)BATCH * ED * C_CH * 16 + (size_t)BATCH * ED * C_CH) * 4);

    dim3 b256(256);
    dim3 b512(512);
    const int MT = (ROWS + 127) / 128;            // 25 M-tiles
    const int MT4 = (ROWS + 255) / 256;           // 13 M-tiles (WM=4)
    const int SCAN_BLOCKS = BATCH * C_CH * EGB;   // 1536
    const int PREP_BLOCKS = ROWS + (INW_F4 + XW_F4 + OW_F4 + DTW_U + 255) / 256;
    const int RED_BLOCKS = (ROWS * 96 + 255) / 256;

    // ---- patch embed: im2col + pe_w->bf16 (fused), MFMA GEMM+bias -> X ----
    im2col_kernel<<<(ROWS * DM + PE_F4 * 4 + 255) / 256, b256, 0, stream>>>(
        rgb, timg, XC, pe_w, PEB);
    gemm_mfma<EPI_BIAS, false, false, false, false><<<dim3(DM / 128, MT), b256, 0, stream>>>(
        XC, DM, PEB, DM, pe_b, X, nullptr, DM, ROWS, DM, DM, DM);

    for (int i = 0; i < 8; ++i) {
        const float* in_wi = in_w + (size_t)i * 2 * ED * DM;
        const float* cwi   = cw   + (size_t)i * ED * 4;
        const float* cbi   = cb   + (size_t)i * ED;
        const float* xwi   = xw   + (size_t)i * 80 * ED;
        const float* dtwi  = dtw  + (size_t)i * ED * DTR;
        const float* dtbi  = dtb  + (size_t)i * ED;
        const float* ali   = alog + (size_t)i * ED * NST;
        const float* dvi   = dvec + (size_t)i * ED;
        const float* owi   = ow   + (size_t)i * DM * ED;
        const float* nwi   = nw   + (size_t)i * DM;

        // prep: weights -> bf16 (incl. dtw zero-padded to K=64) + rmsnorm
        prep_kernel<<<PREP_BLOCKS, b256, 0, stream>>>(
            in_wi, INWB, xwi, XWB, owi, OWB, dtwi, DTWB, X, nwi, XN);
        // [xc | z] = xn @ in_w^T  (256x128 tile, 8 waves: WM=4)
        gemm_mfma<EPI_STORE, true, true, false, false, 4><<<dim3(2 * ED / 128, MT4), b512, 0, stream>>>(
            XN, DM, INWB, DM, nullptr, XC, Zb, ED, ROWS, 2 * ED, DM, DM);
        // xin = silu(causal_conv(xc) + cb)   (overwrites INWB -- after in_proj)
        conv_silu_kernel<<<(ROWS * ED + 255) / 256, b256, 0, stream>>>(
            XC, cwi, cbi, XIN);
        // dbc = xin @ xw^T  (MFMA, N=80 in one 128-tile, split-K=6, fp32
        // partials in d_out, then reduce -> DBC fp32 + DBC48 bf16)
        gemm_mfma<EPI_STORE, false, false, false, true><<<dim3(1, MT, XP_Z), b256, 0, stream>>>(
            XIN, ED, XWB, ED, nullptr, POUT, nullptr, 80, ROWS, 80, ED, ED / XP_Z);
        reduce_partials_kernel<<<RED_BLOCKS, b256, 0, stream>>>(
            POUT, DBC, DBC48);
        // delta = softplus(dbc48 @ dtwb^T + dtb) -> DEL bf16  (MFMA, K=64 pad)
        gemm_mfma<EPI_BIAS_SOFTPLUS, true, false, false, false><<<dim3(ED / 128, MT), b256, 0, stream>>>(
            DBC48, 64, DTWB, 64, dtbi, DEL, nullptr, ED, ROWS, ED, 64, 64);
        // chunked scan: pass1 summaries -> pass2 seeded scan + y  -> XC
        scan_part1<<<SCAN_BLOCKS, 64, 0, stream>>>(
            DEL, XIN, DBC, ali, HEND, SDL);
        scan_part2<<<SCAN_BLOCKS, 64, 0, stream>>>(
            DEL, XIN, DBC, Zb, ali, dvi, HEND, SDL, XC);
        // x += y @ ow^T   (MFMA, split-K z=2, atomic fp32 accumulate into X)
        gemm_mfma<EPI_ADD, false, false, true, false><<<dim3(DM / 128, MT, 2), b256, 0, stream>>>(
            XC, ED, OWB, ED, nullptr, X, nullptr, DM, ROWS, DM, ED, ED / 2);
    }

    out_transpose_kernel<<<(ROWS * DM + 255) / 256, b256, 0, stream>>>(
        X, (float*)d_out);
}

// Round 7
// 1629.868 us; speedup vs baseline: 1.1163x; 1.1163x over previous
//
#include <hip/hip_runtime.h>
#include <cstddef>
#include <cstdint>

// ---- model dims ----
#define L_TOK 392
#define BATCH 8
#define DM    768
#define ED    1536
#define NST   16
#define DTR   48
#define ROWS  (BATCH * L_TOK)   // 3136

// chunked scan
#define C_CH 8
#define CLEN 49                 // L_TOK / C_CH
#define EGB  24                 // ED/64 e-groups

// x_proj split-K (6 so POUT [6.02MB] + OWB fit in d_out)
#define XP_Z  6

// Workspace ~49 MB -- do NOT grow d_ws. Scratch with disjoint lifetimes
// (x_proj partials POUT, scan summaries HEND/SDL, bf16 ow copy OWB) lives in
// d_out, dead until out_transpose. bf16 weight copies alias dead ws buffers.
// This round: exact revert to the round-3 structure (best measured, 1733us);
// r4-r6 deltas (prep fusion, MFMA dt_proj, counted vmcnt, WM=4) all measured
// neutral-to-negative and are removed.

typedef unsigned short ushortT;
typedef __bf16 bf16x8 __attribute__((ext_vector_type(8)));
typedef unsigned short us8 __attribute__((ext_vector_type(8)));
typedef unsigned short us4 __attribute__((ext_vector_type(4)));
typedef float f32x4 __attribute__((ext_vector_type(4)));

#define LOG2E 1.4426950408889634f

__device__ __forceinline__ float bf2f(ushortT u) {
    union { unsigned int i; float f; } v; v.i = ((unsigned int)u) << 16; return v.f;
}
__device__ __forceinline__ ushortT f2bf(float f) {
    union { float f; unsigned int i; } v; v.f = f;
    unsigned int r = v.i + 0x7FFFu + ((v.i >> 16) & 1u);   // round-nearest-even
    return (ushortT)(r >> 16);
}

// async global->LDS, 16B per lane; LDS dest is wave-uniform base + lane*16.
__device__ __forceinline__ void gload16(const void* g, void* l) {
    __builtin_amdgcn_global_load_lds(
        (const __attribute__((address_space(1))) void*)g,
        (__attribute__((address_space(3))) void*)l, 16, 0, 0);
}

enum { EPI_STORE = 0, EPI_BIAS = 1, EPI_BIAS_SOFTPLUS = 2, EPI_ADD = 3 };

#define INW_F4 (2 * ED * DM / 4)   // 589824
#define XW_F4  (80 * ED / 4)       // 30720
#define OW_F4  (DM * ED / 4)       // 294912
#define PE_F4  (DM * DM / 4)       // 147456

// ----------------------------------------------------------------------------
// fp32 -> bf16 weight conversion, up to 3 tensors in one dispatch.
// n0/n1/n2 are in float4 units.
// ----------------------------------------------------------------------------
__global__ __launch_bounds__(256)
void convert3_kernel(const float* __restrict__ s0, ushortT* __restrict__ d0, int n0,
                     const float* __restrict__ s1, ushortT* __restrict__ d1, int n1,
                     const float* __restrict__ s2, ushortT* __restrict__ d2, int n2)
{
    int idx = blockIdx.x * 256 + threadIdx.x;
    const float* s; ushortT* d;
    if (idx < n0) { s = s0; d = d0; }
    else if (idx < n0 + n1) { idx -= n0; s = s1; d = d1; }
    else if (idx < n0 + n1 + n2) { idx -= n0 + n1; s = s2; d = d2; }
    else return;
    float4 f = *(const float4*)(s + (size_t)idx * 4);
    us4 h; h.x = f2bf(f.x); h.y = f2bf(f.y); h.z = f2bf(f.z); h.w = f2bf(f.w);
    *(us4*)(d + (size_t)idx * 4) = h;
}

// ----------------------------------------------------------------------------
// Pipelined MFMA GEMM: C[M,N] (epi)= A[M,K](bf16) @ W[N,K](bf16)^T
// 128x128 tile, BK=32, 256 thr = 4 waves (2x2), 4x4 mfma_f32_16x16x32_bf16.
// Staging via global_load_lds width=16 (no VGPR round-trip, no ds_write).
// Simple 2-phase double-buffer with __syncthreads (counted-vmcnt 3-deep and
// WM=4 tiles both measured neutral in r5/r6 -- removed).
// LDS linear [128][32] bf16: staging writes and quad-slot ds_read_b128 reads
// both bank-uniform. Tail rows read in-bounds garbage from adjacent buffers;
// they only affect unstored C entries.
// SPLITK: blockIdx.z covers kchunk; ATOMIC: fp32 atomicAdd epilogue;
// PARTIAL: plain fp32 stores to per-z slices;
// SPLIT: block-uniform output split at column ED (in_proj -> XC | Zb).
// ----------------------------------------------------------------------------
template <int EPI, bool C_BF, bool SPLIT, bool ATOMIC, bool PARTIAL>
__global__ __launch_bounds__(256)
void gemm_mfma(const ushortT* __restrict__ A, int lda,
               const ushortT* __restrict__ W, int ldw,
               const float* __restrict__ bias,
               void* __restrict__ Cv, void* __restrict__ Cv2, int ldc,
               int M, int N, int K, int kchunk)
{
    __shared__ ushortT As[2][128 * 32];
    __shared__ ushortT Ws[2][128 * 32];

    const int tid  = threadIdx.x;
    const int lane = tid & 63;
    const int wave = tid >> 6;
    const int wm   = wave >> 1;        // 0..1
    const int wn   = wave & 1;         // 0..1
    const int quad = lane >> 4;        // 0..3
    const int l16  = lane & 15;        // 0..15

    // XCD-chunked bijective swizzle (m204): each XCD gets a contiguous chunk
    // of x-major flat ids -> blocks sharing an A row-panel share an L2.
    const int gx   = gridDim.x;
    const int nwg  = gx * gridDim.y;
    const int flat = blockIdx.y * gx + blockIdx.x;
    const int q = nwg >> 3, r = nwg & 7;
    const int xcd = flat & 7, sidx = flat >> 3;
    const int swz = (xcd < r ? xcd * (q + 1) : r * (q + 1) + (xcd - r) * q) + sidx;

    const int m0 = (swz / gx) * 128;
    const int n0 = (swz % gx) * 128;
    const int kb = blockIdx.z * kchunk;
    const int KT = kchunk / 32;

    // staging geometry: seg = wave*2+c covers rows [seg*16, seg*16+16);
    // lane covers row seg*16 + (lane>>2), 16B col-slot (lane&3).
    const int srow = lane >> 2;
    const int scol = (lane & 3) * 8;
    const ushortT* aBase = A + (size_t)(m0 + srow) * lda + scol;
    const ushortT* wBase = W + (size_t)(n0 + srow) * ldw + scol;

    auto stage = [&](int buf, int k0) {
#pragma unroll
        for (int c = 0; c < 2; ++c) {
            const int seg = wave * 2 + c;
            gload16(aBase + (size_t)(seg * 16) * lda + k0, &As[buf][seg * 512]);
            gload16(wBase + (size_t)(seg * 16) * ldw + k0, &Ws[buf][seg * 512]);
        }
    };

    f32x4 acc[4][4] = {};

    auto compute = [&](int buf) {
        bf16x8 af[4], bw[4];
#pragma unroll
        for (int t = 0; t < 4; ++t) {
            us8 ta = *(const us8*)&As[buf][(wm * 64 + t * 16 + l16) * 32 + quad * 8];
            af[t] = __builtin_bit_cast(bf16x8, ta);
            us8 tb = *(const us8*)&Ws[buf][(wn * 64 + t * 16 + l16) * 32 + quad * 8];
            bw[t] = __builtin_bit_cast(bf16x8, tb);
        }
#pragma unroll
        for (int i = 0; i < 4; ++i)
#pragma unroll
            for (int j = 0; j < 4; ++j)
                acc[i][j] = __builtin_amdgcn_mfma_f32_16x16x32_bf16(
                    af[i], bw[j], acc[i][j], 0, 0, 0);
    };

    stage(0, kb);
    __syncthreads();

    for (int kt = 0; kt < KT; ++kt) {
        if (kt + 1 < KT) stage((kt & 1) ^ 1, kb + (kt + 1) * 32);  // issue early
        compute(kt & 1);
        __syncthreads();   // drains vmcnt -> next buffer ready
    }

#pragma unroll
    for (int i = 0; i < 4; ++i) {
#pragma unroll
        for (int r2 = 0; r2 < 4; ++r2) {
            int gm = m0 + wm * 64 + i * 16 + quad * 4 + r2;
            if (gm >= M) continue;
#pragma unroll
            for (int j = 0; j < 4; ++j) {
                int gn = n0 + wn * 64 + j * 16 + l16;
                if (gn >= N) continue;
                float v = acc[i][j][r2];
                if (EPI == EPI_BIAS) v += bias[gn];
                void* dst = Cv;
                int cn = gn;
                if (SPLIT && gn >= ED) { dst = Cv2; cn = gn - ED; }  // block-uniform
                size_t off = (size_t)gm * ldc + cn;
                if (PARTIAL) {
                    ((float*)dst)[(size_t)blockIdx.z * M * ldc + off] = v;
                } else if (ATOMIC) {
                    atomicAdd((float*)dst + off, v);
                } else if (C_BF) {
                    ((ushortT*)dst)[off] = f2bf(v);
                } else {
                    float* p = (float*)dst + off;
                    *p = (EPI == EPI_ADD) ? v + *p : v;
                }
            }
        }
    }
}

// ----------------------------------------------------------------------------
// Reduce x_proj split-K partials: DBC[idx] = sum_z POUT[z][idx]
// ----------------------------------------------------------------------------
__global__ __launch_bounds__(256)
void reduce_partials_kernel(const float* __restrict__ P, float* __restrict__ dbc)
{
    int idx = blockIdx.x * 256 + threadIdx.x;
    if (idx >= ROWS * 80) return;
    float s = 0.f;
#pragma unroll
    for (int z = 0; z < XP_Z; ++z)
        s += P[(size_t)z * ROWS * 80 + idx];
    dbc[idx] = s;
}

// ----------------------------------------------------------------------------
// VALU tiled GEMM (dt_proj: K=48).
// ----------------------------------------------------------------------------
template <int EPI, bool A_BF, bool C_BF>
__global__ __launch_bounds__(256)
void gemm_nt(const void* __restrict__ Av, int lda,
             const float* __restrict__ W, int ldw,
             const float* __restrict__ bias,
             void* __restrict__ Cv, int ldc,
             int M, int N, int K)
{
    __shared__ float As[16][68];
    __shared__ float Bs[16][68];
    const int tid = threadIdx.x;
    const int tx  = tid & 15;
    const int ty  = tid >> 4;
    const int bm  = blockIdx.y * 64;
    const int bn  = blockIdx.x * 64;
    const int lr  = tid >> 2;
    const int lk  = (tid & 3) * 4;

    float acc[4][4] = {};

    for (int k0 = 0; k0 < K; k0 += 16) {
        float a0 = 0.f, a1 = 0.f, a2 = 0.f, a3 = 0.f;
        float w0 = 0.f, w1 = 0.f, w2 = 0.f, w3 = 0.f;
        int ga = bm + lr;
        if (ga < M) {
            if (A_BF) {
                const ushortT* A = (const ushortT*)Av;
                ushort4 t = *(const ushort4*)(A + (size_t)ga * lda + k0 + lk);
                a0 = bf2f(t.x); a1 = bf2f(t.y); a2 = bf2f(t.z); a3 = bf2f(t.w);
            } else {
                const float* A = (const float*)Av;
                float4 t = *(const float4*)(A + (size_t)ga * lda + k0 + lk);
                a0 = t.x; a1 = t.y; a2 = t.z; a3 = t.w;
            }
        }
        int gw = bn + lr;
        if (gw < N) {
            float4 t = *(const float4*)(W + (size_t)gw * ldw + k0 + lk);
            w0 = t.x; w1 = t.y; w2 = t.z; w3 = t.w;
        }
        As[lk + 0][lr] = a0; As[lk + 1][lr] = a1;
        As[lk + 2][lr] = a2; As[lk + 3][lr] = a3;
        Bs[lk + 0][lr] = w0; Bs[lk + 1][lr] = w1;
        Bs[lk + 2][lr] = w2; Bs[lk + 3][lr] = w3;
        __syncthreads();
#pragma unroll
        for (int k = 0; k < 16; ++k) {
            float4 a4 = *(const float4*)&As[k][ty * 4];
            float4 b4 = *(const float4*)&Bs[k][tx * 4];
            float a[4] = {a4.x, a4.y, a4.z, a4.w};
            float b[4] = {b4.x, b4.y, b4.z, b4.w};
#pragma unroll
            for (int i = 0; i < 4; ++i)
#pragma unroll
                for (int j = 0; j < 4; ++j)
                    acc[i][j] += a[i] * b[j];
        }
        __syncthreads();
    }

#pragma unroll
    for (int i = 0; i < 4; ++i) {
        int gm = bm + ty * 4 + i;
        if (gm >= M) continue;
#pragma unroll
        for (int j = 0; j < 4; ++j) {
            int gn = bn + tx * 4 + j;
            if (gn >= N) continue;
            float v = acc[i][j];
            if (EPI == EPI_BIAS) v += bias[gn];
            if (EPI == EPI_BIAS_SOFTPLUS) {
                v += bias[gn];
                v = fmaxf(v, 0.f) + log1pf(expf(-fabsf(v)));  // softplus
            }
            size_t off = (size_t)gm * ldc + gn;
            if (C_BF) {
                ((ushortT*)Cv)[off] = f2bf(v);
            } else {
                float* p = (float*)Cv + off;
                *p = (EPI == EPI_ADD) ? v + *p : v;
            }
        }
    }
}

// ----------------------------------------------------------------------------
// RMSNorm: xn[r,:] = x[r,:] * rsqrt(mean(x^2)+1e-5) * w   (768/row, bf16 out)
// ----------------------------------------------------------------------------
__global__ __launch_bounds__(256)
void rmsnorm_kernel(const float* __restrict__ x, const float* __restrict__ w,
                    ushortT* __restrict__ xn)
{
    int r = blockIdx.x;
    const float* xr = x + (size_t)r * DM;
    float v[3];
    float s = 0.f;
#pragma unroll
    for (int i = 0; i < 3; ++i) {
        v[i] = xr[threadIdx.x + i * 256];
        s += v[i] * v[i];
    }
#pragma unroll
    for (int o = 32; o > 0; o >>= 1) s += __shfl_down(s, o, 64);
    __shared__ float wsum[4];
    __shared__ float scale_s;
    int wave = threadIdx.x >> 6;
    if ((threadIdx.x & 63) == 0) wsum[wave] = s;
    __syncthreads();
    if (threadIdx.x == 0) {
        float t = wsum[0] + wsum[1] + wsum[2] + wsum[3];
        scale_s = rsqrtf(t * (1.f / 768.f) + 1e-5f);
    }
    __syncthreads();
    float sc = scale_s;
#pragma unroll
    for (int i = 0; i < 3; ++i) {
        int d = threadIdx.x + i * 256;
        xn[(size_t)r * DM + d] = f2bf(v[i] * sc * w[d]);
    }
}

// ----------------------------------------------------------------------------
// Causal depthwise conv (width 4) + bias + silu; 2 channels per thread
// (ushort2 loads/stores -- 4B/lane instead of 2B/lane, G13).
// ----------------------------------------------------------------------------
__global__ __launch_bounds__(256)
void conv_silu_kernel(const ushortT* __restrict__ xc, const float* __restrict__ cw,
                      const float* __restrict__ cb, ushortT* __restrict__ xin)
{
    int idx = blockIdx.x * 256 + threadIdx.x;
    if (idx >= ROWS * ED / 2) return;
    int e2 = (idx % (ED / 2)) * 2;
    int r  = idx / (ED / 2);
    int l  = r % L_TOK;
    const ushortT* base = xc + (size_t)r * ED + e2;
    ushort2 t0 = *(const ushort2*)(base);
    ushort2 t1 = {0, 0}, t2 = {0, 0}, t3 = {0, 0};
    if (l >= 1) t1 = *(const ushort2*)(base - ED);
    if (l >= 2) t2 = *(const ushort2*)(base - 2 * ED);
    if (l >= 3) t3 = *(const ushort2*)(base - 3 * ED);
    ushort2 out;
#pragma unroll
    for (int c = 0; c < 2; ++c) {
        int e = e2 + c;
        float acc = cb[e] + cw[e * 4 + 3] * bf2f(c ? t0.y : t0.x);
        acc += cw[e * 4 + 2] * bf2f(c ? t1.y : t1.x);
        acc += cw[e * 4 + 1] * bf2f(c ? t2.y : t2.x);
        acc += cw[e * 4 + 0] * bf2f(c ? t3.y : t3.x);
        ushortT o = f2bf(acc / (1.f + __expf(-acc)));  // silu
        if (c) out.y = o; else out.x = o;
    }
    *(ushort2*)(xin + (size_t)r * ED + e2) = out;
}

// ----------------------------------------------------------------------------
// Chunked selective scan, pass 1: per (b,e,chunk) local end-state + sum_delta.
// a[] is pre-scaled by log2(e) so the inner loop uses raw v_exp_f32 (2^x).
// ----------------------------------------------------------------------------
__global__ __launch_bounds__(64)
void scan_part1(const ushortT* __restrict__ delta, const ushortT* __restrict__ xin,
                const float* __restrict__ dbc, const float* __restrict__ a_log,
                float* __restrict__ hend, float* __restrict__ sdl)
{
    __shared__ float BsL[CLEN * 16];
    const int tid = threadIdx.x;
    const int bid = blockIdx.x;
    const int eg = bid % EGB;
    const int c  = (bid / EGB) % C_CH;
    const int b  = bid / (EGB * C_CH);
    const int e  = eg * 64 + tid;
    const int l0 = c * CLEN;
    const int rb = b * L_TOK + l0;

    for (int i = tid; i < CLEN * 16; i += 64) {
        int s = i >> 4, n = i & 15;
        BsL[i] = dbc[(size_t)(rb + s) * 80 + 48 + n];
    }
    __syncthreads();

    float a[16];
    const float* ar = a_log + (size_t)e * 16;
#pragma unroll
    for (int n = 0; n < 16; ++n) a[n] = -__expf(ar[n]) * LOG2E;

    float h[16];
#pragma unroll
    for (int n = 0; n < 16; ++n) h[n] = 0.f;
    float sum_dl = 0.f;

    const size_t base = (size_t)rb * ED + e;
    float rdl[7], rxi[7];
#pragma unroll
    for (int j = 0; j < 7; ++j) {
        rdl[j] = bf2f(delta[base + (size_t)j * ED]);
        rxi[j] = bf2f(xin[base + (size_t)j * ED]);
    }
    for (int s0 = 0; s0 < CLEN; s0 += 7) {
#pragma unroll
        for (int j = 0; j < 7; ++j) {
            const int s = s0 + j;
            float dl = rdl[j], xi = rxi[j];
            int sp = s + 7; if (sp > CLEN - 1) sp = CLEN - 1;   // clamped prefetch
            rdl[j] = bf2f(delta[base + (size_t)sp * ED]);
            rxi[j] = bf2f(xin[base + (size_t)sp * ED]);
            float dlxi = dl * xi;
            sum_dl += dl;
#pragma unroll
            for (int n = 0; n < 16; ++n)
                h[n] = __builtin_amdgcn_exp2f(dl * a[n]) * h[n] + dlxi * BsL[s * 16 + n];
        }
    }

    float* hp = hend + (((size_t)b * ED + e) * C_CH + c) * 16;
#pragma unroll
    for (int n = 0; n < 16; ++n) hp[n] = h[n];
    sdl[((size_t)b * ED + e) * C_CH + c] = sum_dl;
}

// ----------------------------------------------------------------------------
// Chunked scan, pass 2: combine predecessor summaries, re-run chunk, emit y.
// ----------------------------------------------------------------------------
__global__ __launch_bounds__(64)
void scan_part2(const ushortT* __restrict__ delta, const ushortT* __restrict__ xin,
                const float* __restrict__ dbc, const ushortT* __restrict__ zb,
                const float* __restrict__ a_log, const float* __restrict__ dvec,
                const float* __restrict__ hend, const float* __restrict__ sdl,
                ushortT* __restrict__ y)
{
    __shared__ float BsL[CLEN * 16];
    __shared__ float CsL[CLEN * 16];
    const int tid = threadIdx.x;
    const int bid = blockIdx.x;
    const int eg = bid % EGB;
    const int c  = (bid / EGB) % C_CH;
    const int b  = bid / (EGB * C_CH);
    const int e  = eg * 64 + tid;
    const int l0 = c * CLEN;
    const int rb = b * L_TOK + l0;

    for (int i = tid; i < CLEN * 16; i += 64) {
        int s = i >> 4, n = i & 15;
        size_t row = (size_t)(rb + s) * 80;
        BsL[i] = dbc[row + 48 + n];
        CsL[i] = dbc[row + 64 + n];
    }
    __syncthreads();

    float a[16];
    const float* ar = a_log + (size_t)e * 16;
#pragma unroll
    for (int n = 0; n < 16; ++n) a[n] = -__expf(ar[n]) * LOG2E;
    const float dcf = dvec[e];

    float h[16];
#pragma unroll
    for (int n = 0; n < 16; ++n) h[n] = 0.f;
    const float* hb = hend + (((size_t)b * ED + e) * C_CH) * 16;
    const float* sb = sdl + ((size_t)b * ED + e) * C_CH;
    for (int cc = 0; cc < c; ++cc) {
        float sv = sb[cc];
#pragma unroll
        for (int n = 0; n < 16; ++n)
            h[n] = __builtin_amdgcn_exp2f(a[n] * sv) * h[n] + hb[cc * 16 + n];
    }

    const size_t base = (size_t)rb * ED + e;
    float rdl[7], rxi[7], rz[7];
#pragma unroll
    for (int j = 0; j < 7; ++j) {
        rdl[j] = bf2f(delta[base + (size_t)j * ED]);
        rxi[j] = bf2f(xin[base + (size_t)j * ED]);
        rz[j]  = bf2f(zb[base + (size_t)j * ED]);
    }
    for (int s0 = 0; s0 < CLEN; s0 += 7) {
#pragma unroll
        for (int j = 0; j < 7; ++j) {
            const int s = s0 + j;
            float dl = rdl[j], xi = rxi[j], z = rz[j];
            int sp = s + 7; if (sp > CLEN - 1) sp = CLEN - 1;   // clamped prefetch
            rdl[j] = bf2f(delta[base + (size_t)sp * ED]);
            rxi[j] = bf2f(xin[base + (size_t)sp * ED]);
            rz[j]  = bf2f(zb[base + (size_t)sp * ED]);
            float dlxi = dl * xi;
            float yv = 0.f;
#pragma unroll
            for (int n = 0; n < 16; ++n) {
                h[n] = __builtin_amdgcn_exp2f(dl * a[n]) * h[n] + dlxi * BsL[s * 16 + n];
                yv += h[n] * CsL[s * 16 + n];
            }
            yv += dcf * xi;
            float sz = z / (1.f + __expf(-z));
            y[base + (size_t)s * ED] = f2bf(yv * sz);
        }
    }
}

// ----------------------------------------------------------------------------
// im2col for patch embed + pe_w fp32->bf16 convert (fused, block-range split).
// ----------------------------------------------------------------------------
__global__ __launch_bounds__(256)
void im2col_kernel(const float* __restrict__ rgb, const float* __restrict__ timg,
                   ushortT* __restrict__ P,
                   const float* __restrict__ pe_w, ushortT* __restrict__ peb)
{
    int idx = blockIdx.x * 256 + threadIdx.x;
    if (idx < ROWS * DM) {
        int k = idx % DM;
        int r = idx / DM;
        int b = r / L_TOK;
        int l = r % L_TOK;
        const float* img = (l < 196) ? rgb : timg;
        int p  = (l < 196) ? l : l - 196;
        int py = p / 14, px = p % 14;
        int c  = k >> 8;
        int ph = (k >> 4) & 15;
        int pw = k & 15;
        P[idx] = f2bf(img[(((size_t)b * 3 + c) * 224 + (py * 16 + ph)) * 224 + (px * 16 + pw)]);
        return;
    }
    int u = idx - ROWS * DM;
    if (u < PE_F4) {
        float4 f = *(const float4*)(pe_w + (size_t)u * 4);
        us4 h; h.x = f2bf(f.x); h.y = f2bf(f.y); h.z = f2bf(f.z); h.w = f2bf(f.w);
        *(us4*)(peb + (size_t)u * 4) = h;
    }
}

// ----------------------------------------------------------------------------
// Output: out[(l*768 + d)*8 + b] = x[b, l, d]
// ----------------------------------------------------------------------------
__global__ __launch_bounds__(256)
void out_transpose_kernel(const float* __restrict__ x, float* __restrict__ out)
{
    int idx = blockIdx.x * 256 + threadIdx.x;
    if (idx >= ROWS * DM) return;
    int b = idx & 7;
    int d = (idx >> 3) % DM;
    int l = idx / (8 * DM);
    out[idx] = x[((size_t)(b * L_TOK + l)) * DM + d];
}

// ----------------------------------------------------------------------------
extern "C" void kernel_launch(void* const* d_in, const int* in_sizes, int n_in,
                              void* d_out, int out_size, void* d_ws, size_t ws_size,
                              hipStream_t stream)
{
    (void)in_sizes; (void)n_in; (void)out_size; (void)ws_size;

    const float* rgb  = (const float*)d_in[0];
    const float* timg = (const float*)d_in[1];
    const float* pe_w = (const float*)d_in[2];   // [768, 3,16,16] -> [768][768]
    const float* pe_b = (const float*)d_in[3];
    const float* in_w = (const float*)d_in[4];   // [8, 3072, 768]
    const float* cw   = (const float*)d_in[5];   // [8, 1536, 1, 4]
    const float* cb   = (const float*)d_in[6];   // [8, 1536]
    const float* xw   = (const float*)d_in[7];   // [8, 80, 1536]
    const float* dtw  = (const float*)d_in[8];   // [8, 1536, 48]
    const float* dtb  = (const float*)d_in[9];   // [8, 1536]
    const float* alog = (const float*)d_in[10];  // [8, 1536, 16]
    const float* dvec = (const float*)d_in[11];  // [8, 1536]
    const float* ow   = (const float*)d_in[12];  // [8, 768, 1536]
    const float* nw   = (const float*)d_in[13];  // [8, 768]

    char* p = (char*)d_ws;
    float*   X   = (float*)p;    p += (size_t)ROWS * DM * 4;
    ushortT* XC  = (ushortT*)p;  p += (size_t)ROWS * ED * 2;   // conv-in / patches / y
    ushortT* Zb  = (ushortT*)p;  p += (size_t)ROWS * ED * 2;
    ushortT* XIN = (ushortT*)p;  p += (size_t)ROWS * ED * 2;
    ushortT* DEL = (ushortT*)p;  p += (size_t)ROWS * ED * 2;   // delta; front = xn
    float*   DBC = (float*)p;    p += (size_t)ROWS * 80 * 4;
    ushortT* XN  = DEL;          // overlay: xn dead before delta is written

    // bf16 weight copies, aliased onto dead buffers (lifetimes checked):
    //   INWB in XIN  : written at convert, read by in_proj, dies at conv_silu
    //   XWB  in DBC  : written at convert, read by x_proj, dies at reduce
    //   PEB  in Zb   : written at im2col, dies at layer0 in_proj
    ushortT* INWB = XIN;
    ushortT* XWB  = (ushortT*)DBC;
    ushortT* PEB  = Zb;

    // d_out scratch layout (dead until out_transpose):
    //   POUT : [0, 6.02M)   x_proj fp32 partials, dies at reduce
    //   HEND : [0, 6.29M) + SDL [6.29M, 6.68M)  born scan1 (after reduce+dt)
    //   OWB  : [6.68M, 9.04M)  bf16 ow copy, born convert, dies out_proj
    float* POUT = (float*)d_out;
    float* HEND = (float*)d_out;
    float* SDL  = HEND + (size_t)BATCH * ED * C_CH * 16;
    ushortT* OWB = (ushortT*)((char*)d_out +
                   ((size_t)BATCH * ED * C_CH * 16 + (size_t)BATCH * ED * C_CH) * 4);

    dim3 b256(256);
    const int MT = (ROWS + 127) / 128;            // 25 M-tiles
    const int SCAN_BLOCKS = BATCH * C_CH * EGB;   // 1536
    const int CVT_BLOCKS = (INW_F4 + XW_F4 + OW_F4 + 255) / 256;

    // ---- patch embed: im2col + pe_w->bf16 (fused), MFMA GEMM+bias -> X ----
    im2col_kernel<<<(ROWS * DM + PE_F4 + 255) / 256, b256, 0, stream>>>(
        rgb, timg, XC, pe_w, PEB);
    gemm_mfma<EPI_BIAS, false, false, false, false><<<dim3(DM / 128, MT), b256, 0, stream>>>(
        XC, DM, PEB, DM, pe_b, X, nullptr, DM, ROWS, DM, DM, DM);

    for (int i = 0; i < 8; ++i) {
        const float* in_wi = in_w + (size_t)i * 2 * ED * DM;
        const float* cwi   = cw   + (size_t)i * ED * 4;
        const float* cbi   = cb   + (size_t)i * ED;
        const float* xwi   = xw   + (size_t)i * 80 * ED;
        const float* dtwi  = dtw  + (size_t)i * ED * DTR;
        const float* dtbi  = dtb  + (size_t)i * ED;
        const float* ali   = alog + (size_t)i * ED * NST;
        const float* dvi   = dvec + (size_t)i * ED;
        const float* owi   = ow   + (size_t)i * DM * ED;
        const float* nwi   = nw   + (size_t)i * DM;

        // all three weight tensors -> bf16 in one dispatch (targets dead here)
        convert3_kernel<<<CVT_BLOCKS, b256, 0, stream>>>(
            in_wi, INWB, INW_F4, xwi, XWB, XW_F4, owi, OWB, OW_F4);
        // xn = rmsnorm(x)  -> XN (bf16, overlaid on DEL)
        rmsnorm_kernel<<<ROWS, b256, 0, stream>>>(X, nwi, XN);
        // [xc | z] = xn @ in_w^T  (single MFMA dispatch, block-uniform split)
        gemm_mfma<EPI_STORE, true, true, false, false><<<dim3(2 * ED / 128, MT), b256, 0, stream>>>(
            XN, DM, INWB, DM, nullptr, XC, Zb, ED, ROWS, 2 * ED, DM, DM);
        // xin = silu(causal_conv(xc) + cb)   (overwrites INWB -- after in_proj)
        conv_silu_kernel<<<(ROWS * ED / 2 + 255) / 256, b256, 0, stream>>>(
            XC, cwi, cbi, XIN);
        // dbc = xin @ xw^T  (MFMA, N=80 in one 128-tile, split-K=6, fp32
        // partials in d_out, then reduce -> DBC; reduce overwrites XWB)
        gemm_mfma<EPI_STORE, false, false, false, true><<<dim3(1, MT, XP_Z), b256, 0, stream>>>(
            XIN, ED, XWB, ED, nullptr, POUT, nullptr, 80, ROWS, 80, ED, ED / XP_Z);
        reduce_partials_kernel<<<(ROWS * 80 + 255) / 256, b256, 0, stream>>>(
            POUT, DBC);
        // delta = softplus(dbc[:, :48] @ dtw^T + dtb) -> DEL bf16   (VALU: K=48)
        gemm_nt<EPI_BIAS_SOFTPLUS, false, true><<<dim3(ED / 64, ROWS / 64), b256, 0, stream>>>(
            DBC, 80, dtwi, DTR, dtbi, DEL, ED, ROWS, ED, DTR);
        // chunked scan: pass1 summaries -> pass2 seeded scan + y  -> XC
        scan_part1<<<SCAN_BLOCKS, 64, 0, stream>>>(
            DEL, XIN, DBC, ali, HEND, SDL);
        scan_part2<<<SCAN_BLOCKS, 64, 0, stream>>>(
            DEL, XIN, DBC, Zb, ali, dvi, HEND, SDL, XC);
        // x += y @ ow^T   (MFMA, split-K z=2, atomic fp32 accumulate into X)
        gemm_mfma<EPI_ADD, false, false, true, false><<<dim3(DM / 128, MT, 2), b256, 0, stream>>>(
            XC, ED, OWB, ED, nullptr, X, nullptr, DM, ROWS, DM, ED, ED / 2);
    }

    out_transpose_kernel<<<(ROWS * DM + 255) / 256, b256, 0, stream>>>(
        X, (float*)d_out);
}